// Round 6
// baseline (1507.505 us; speedup 1.0000x reference)
//
#include <hip/hip_runtime.h>
#include <math.h>

// Problem constants
#define Bz  16
#define Dz  512
#define Tz  4096
#define NCB 9
#define Kz  1024
#define CD  8

// Output layout (floats): z_q | codes | latents | cl | cbl
static const unsigned long long OZQ   = 0ull;
static const unsigned long long OCODE = 33554432ull;             // 16*512*4096
static const unsigned long long OLAT  = 34144256ull;             // + 16*9*4096
static const unsigned long long OCL   = 38862848ull;             // + 16*72*4096

#define WS_CBN2_OFF (NCB * CD * Kz)   // ws: cbnT[9][8][1024] then cbn2[9][1024]

// ---------------------------------------------------------------------------
// Prep: normalized codebooks (transposed) + their squared norms; zero loss slots
// ---------------------------------------------------------------------------
__global__ __launch_bounds__(1024) void rvq_prep(const float* __restrict__ cb,
                                                 float* __restrict__ ws,
                                                 float* __restrict__ out) {
    const int i = blockIdx.x;    // codebook 0..8
    const int k = threadIdx.x;   // entry 0..1023
    const float* row = cb + ((size_t)i * Kz + k) * CD;
    float v[CD];
#pragma unroll
    for (int c = 0; c < CD; ++c) v[c] = row[c];
    float ss = 0.f;
#pragma unroll
    for (int c = 0; c < CD; ++c) ss += v[c] * v[c];
    const float den = fmaxf(sqrtf(ss), 1e-12f);   // F.normalize eps clamp
    float cb2 = 0.f;
#pragma unroll
    for (int c = 0; c < CD; ++c) {
        float e = v[c] / den;
        ws[((size_t)i * CD + c) * Kz + k] = e;     // cbnT[i][c][k]
        cb2 += e * e;
    }
    ws[WS_CBN2_OFF + (size_t)i * Kz + k] = cb2;
    if (i == 0 && k == 0) { out[OCL] = 0.f; out[OCL + 1] = 0.f; }
}

// ---------------------------------------------------------------------------
// DPP wave64 reductions (classic gfx9 sequence) — zero DS-pipe traffic.
// sum: bound_ctrl=1 (invalid lanes contribute 0); result valid in lane 63.
// min: bound_ctrl=0 with old=self (invalid lanes -> no-op).
// ---------------------------------------------------------------------------
template <int CTRL>
__device__ __forceinline__ float dpp_add_t(float v) {
    int t = __builtin_amdgcn_update_dpp(0, __float_as_int(v), CTRL, 0xf, 0xf, true);
    return v + __int_as_float(t);
}
__device__ __forceinline__ float wave_sum64(float v) {
    v = dpp_add_t<0x111>(v);   // row_shr:1
    v = dpp_add_t<0x112>(v);   // row_shr:2
    v = dpp_add_t<0x114>(v);   // row_shr:4
    v = dpp_add_t<0x118>(v);   // row_shr:8
    v = dpp_add_t<0x142>(v);   // row_bcast:15
    v = dpp_add_t<0x143>(v);   // row_bcast:31
    return __int_as_float(__builtin_amdgcn_readlane(__float_as_int(v), 63));
}
template <int CTRL>
__device__ __forceinline__ float dpp_min_t(float v) {
    int t = __builtin_amdgcn_update_dpp(__float_as_int(v), __float_as_int(v),
                                        CTRL, 0xf, 0xf, false);
    return fminf(v, __int_as_float(t));
}
__device__ __forceinline__ float wave_min64(float v) {
    v = dpp_min_t<0x111>(v);
    v = dpp_min_t<0x112>(v);
    v = dpp_min_t<0x114>(v);
    v = dpp_min_t<0x118>(v);
    v = dpp_min_t<0x142>(v);
    v = dpp_min_t<0x143>(v);
    return __int_as_float(__builtin_amdgcn_readlane(__float_as_int(v), 63));
}

// ---------------------------------------------------------------------------
// Main: 1024 threads = 16 waves; block covers 32 t-columns; wave owns 2 cols.
// DS-pipe diet vs round 4:
//   - cbnT in LDS as plain [8][1024]; lane reads k = mq*256+lane*4 -> every
//     ds_read_b128 is contiguous 16B/lane (conflict-free).
//   - w_in / b_in / cbn2 / winner codebook rows read from GLOBAL (L1-hot,
//     VMEM pipe idle) -> s_win/s_cbn2 staging and their conflicts deleted.
//   - all shuffle reductions -> VALU DPP (wave_sum64 / wave_min64); z_e and
//     winner indices become wave-uniform -> no en broadcast, uniform fetch.
//   - latents/codes written directly to global (L2 merges adjacent waves).
// LDS 33 KB, target <=64 VGPR -> 2 blocks/CU, 32 waves/CU.
// ---------------------------------------------------------------------------
__global__ __launch_bounds__(1024)
void rvq_main(
    const float* __restrict__ z,
    const float* __restrict__ w_in,
    const float* __restrict__ b_in,
    const float* __restrict__ w_out,
    const float* __restrict__ b_out,
    const float* __restrict__ cb,
    const float* __restrict__ ws,
    float* __restrict__ out)
{
    __shared__ float s_cbnT[CD * Kz];   // 32768 B, plain [c][k]
    __shared__ float s_red[16];
    float* s_tr = s_cbnT;               // alias: 32x132 transpose scratch (4224 floats)

    const int tid  = threadIdx.x;
    const int wave = tid >> 6;                   // 0..15
    const int lane = tid & 63;
    const int bb   = blockIdx.x;                 // 0..2047
    const int b    = bb >> 7;                    // batch
    const int t0blk = (bb & 127) << 5;           // block's 32-column base

    const size_t zbase = (size_t)b * Dz * Tz + t0blk;

    // ---- coalesced z load -> LDS transpose -> registers (into res2) ----
    float res2[2][8];
#pragma unroll 1
    for (int c = 0; c < 4; ++c) {
        {
            const int r = tid >> 3;              // 0..127
            const int u = (tid & 7) * 4;         // 0..28
            float4 v = *(const float4*)(z + zbase + (size_t)(c * 128 + r) * Tz + u);
            s_tr[(u + 0) * 132 + r] = v.x;
            s_tr[(u + 1) * 132 + r] = v.y;
            s_tr[(u + 2) * 132 + r] = v.z;
            s_tr[(u + 3) * 132 + r] = v.w;
        }
        __syncthreads();
        if ((lane >> 4) == c) {
            const int lr = (lane & 15) * 8;
#pragma unroll
            for (int col = 0; col < 2; ++col)
#pragma unroll
                for (int j = 0; j < 8; ++j)
                    res2[col][j] = s_tr[(wave * 2 + col) * 132 + lr + j];
        }
        __syncthreads();
    }

    float lsum = 0.f;

#pragma unroll 1
    for (int i = 0; i < NCB; ++i) {
        __syncthreads();   // previous step's LDS reads done
        // ---- stage cbnT: straight copy, conflict-free ----
        {
            const float4* srcT = (const float4*)(ws + (size_t)i * 8192);
            float4 v0 = srcT[tid];
            float4 v1 = srcT[tid + 1024];
            ((float4*)s_cbnT)[tid]        = v0;
            ((float4*)s_cbnT)[tid + 1024] = v1;
        }
        __syncthreads();

        // ---- z_e = w_in @ residual + b_in : DPP sums -> 16 uniform scalars ----
        float zz[2][8];
        {
            const float* wb = w_in + (size_t)i * 4096 + lane * 8;
#pragma unroll
            for (int c = 0; c < 8; ++c) {
                float4 wa = *(const float4*)(wb + c * 512);
                float4 wc = *(const float4*)(wb + c * 512 + 4);
                float q0 = wa.x * res2[0][0];
                float q1 = wa.x * res2[1][0];
                q0 = fmaf(wa.y, res2[0][1], q0); q1 = fmaf(wa.y, res2[1][1], q1);
                q0 = fmaf(wa.z, res2[0][2], q0); q1 = fmaf(wa.z, res2[1][2], q1);
                q0 = fmaf(wa.w, res2[0][3], q0); q1 = fmaf(wa.w, res2[1][3], q1);
                q0 = fmaf(wc.x, res2[0][4], q0); q1 = fmaf(wc.x, res2[1][4], q1);
                q0 = fmaf(wc.y, res2[0][5], q0); q1 = fmaf(wc.y, res2[1][5], q1);
                q0 = fmaf(wc.z, res2[0][6], q0); q1 = fmaf(wc.z, res2[1][6], q1);
                q0 = fmaf(wc.w, res2[0][7], q0); q1 = fmaf(wc.w, res2[1][7], q1);
                zz[0][c] = wave_sum64(q0);
                zz[1][c] = wave_sum64(q1);
            }
            float4 bA = *(const float4*)(b_in + i * 8);
            float4 bB = *(const float4*)(b_in + i * 8 + 4);
            zz[0][0] += bA.x; zz[1][0] += bA.x;
            zz[0][1] += bA.y; zz[1][1] += bA.y;
            zz[0][2] += bA.z; zz[1][2] += bA.z;
            zz[0][3] += bA.w; zz[1][3] += bA.w;
            zz[0][4] += bB.x; zz[1][4] += bB.x;
            zz[0][5] += bB.y; zz[1][5] += bB.y;
            zz[0][6] += bB.z; zz[1][6] += bB.z;
            zz[0][7] += bB.w; zz[1][7] += bB.w;
        }

        // ---- latents -> global direct (values are uniform; lane 2c+g writes zz[g][c]) ----
        {
            float v = zz[0][0];
            v = (lane == 1)  ? zz[1][0] : v;
            v = (lane == 2)  ? zz[0][1] : v;
            v = (lane == 3)  ? zz[1][1] : v;
            v = (lane == 4)  ? zz[0][2] : v;
            v = (lane == 5)  ? zz[1][2] : v;
            v = (lane == 6)  ? zz[0][3] : v;
            v = (lane == 7)  ? zz[1][3] : v;
            v = (lane == 8)  ? zz[0][4] : v;
            v = (lane == 9)  ? zz[1][4] : v;
            v = (lane == 10) ? zz[0][5] : v;
            v = (lane == 11) ? zz[1][5] : v;
            v = (lane == 12) ? zz[0][6] : v;
            v = (lane == 13) ? zz[1][6] : v;
            v = (lane == 14) ? zz[0][7] : v;
            v = (lane == 15) ? zz[1][7] : v;
            if (lane < 16)
                out[OLAT + ((size_t)b * 72 + i * 8 + (lane >> 1)) * Tz
                    + t0blk + wave * 2 + (lane & 1)] = v;
        }

        // ---- l2-normalize (uniform) ----
        float ss0 = 0.f, ss1 = 0.f;
#pragma unroll
        for (int c = 0; c < 8; ++c) {
            ss0 = fmaf(zz[0][c], zz[0][c], ss0);
            ss1 = fmaf(zz[1][c], zz[1][c], ss1);
        }
        const float den0 = fmaxf(sqrtf(ss0), 1e-12f);
        const float den1 = fmaxf(sqrtf(ss1), 1e-12f);
        float en[2][8];
#pragma unroll
        for (int c = 0; c < 8; ++c) {
            en[0][c] = zz[0][c] / den0;
            en[1][c] = zz[1][c] / den1;
        }

        // ---- distance scoring: lane owns k = mq*256 + lane*4 + q (conflict-free) ----
        // score = cb2 - 2*dot (en2 constant per column -> irrelevant for argmin)
        float best0 = 1e30f, best1 = 1e30f;
        int   bi0 = 0, bi1 = 0;
        const float* c2base = ws + WS_CBN2_OFF + (size_t)i * Kz;
#pragma unroll
        for (int mq = 0; mq < 4; ++mq) {
            const int kb = mq * 256 + lane * 4;
            float4 c2 = *(const float4*)(c2base + kb);
            float d00 = 0.f, d01 = 0.f, d02 = 0.f, d03 = 0.f;
            float d10 = 0.f, d11 = 0.f, d12 = 0.f, d13 = 0.f;
#pragma unroll
            for (int c = 0; c < 8; ++c) {
                float4 v = *(const float4*)&s_cbnT[c * 1024 + kb];
                d00 = fmaf(en[0][c], v.x, d00); d10 = fmaf(en[1][c], v.x, d10);
                d01 = fmaf(en[0][c], v.y, d01); d11 = fmaf(en[1][c], v.y, d11);
                d02 = fmaf(en[0][c], v.z, d02); d12 = fmaf(en[1][c], v.z, d12);
                d03 = fmaf(en[0][c], v.w, d03); d13 = fmaf(en[1][c], v.w, d13);
            }
            float dist;
            dist = fmaf(-2.f, d00, c2.x); if (dist < best0) { best0 = dist; bi0 = kb + 0; }
            dist = fmaf(-2.f, d01, c2.y); if (dist < best0) { best0 = dist; bi0 = kb + 1; }
            dist = fmaf(-2.f, d02, c2.z); if (dist < best0) { best0 = dist; bi0 = kb + 2; }
            dist = fmaf(-2.f, d03, c2.w); if (dist < best0) { best0 = dist; bi0 = kb + 3; }
            dist = fmaf(-2.f, d10, c2.x); if (dist < best1) { best1 = dist; bi1 = kb + 0; }
            dist = fmaf(-2.f, d11, c2.y); if (dist < best1) { best1 = dist; bi1 = kb + 1; }
            dist = fmaf(-2.f, d12, c2.z); if (dist < best1) { best1 = dist; bi1 = kb + 2; }
            dist = fmaf(-2.f, d13, c2.w); if (dist < best1) { best1 = dist; bi1 = kb + 3; }
        }
        // wave argmin: DPP min + ballot + readlane -> uniform winner index
        const float g0 = wave_min64(best0);
        const float g1 = wave_min64(best1);
        const int wl0 = __ffsll((long long)(unsigned long long)__ballot(best0 == g0)) - 1;
        const int wl1 = __ffsll((long long)(unsigned long long)__ballot(best1 == g1)) - 1;
        const int k0 = __builtin_amdgcn_readlane(bi0, wl0);
        const int k1 = __builtin_amdgcn_readlane(bi1, wl1);

        // ---- fetch raw codebook rows for the 2 winners (uniform address, L1/L2) ----
        const float* cr0 = cb + ((size_t)i * Kz + k0) * CD;
        float4 qa = *(const float4*)cr0, qb = *(const float4*)(cr0 + 4);
        float cq0[8] = {qa.x, qa.y, qa.z, qa.w, qb.x, qb.y, qb.z, qb.w};
        const float* cr1 = cb + ((size_t)i * Kz + k1) * CD;
        float4 qc = *(const float4*)cr1, qd = *(const float4*)(cr1 + 4);
        float cq1[8] = {qc.x, qc.y, qc.z, qc.w, qd.x, qd.y, qd.z, qd.w};

        // ---- codes -> global direct ----
        if (lane == 0) {
            out[OCODE + ((size_t)b * NCB + i) * Tz + t0blk + wave * 2]     = (float)k0;
            out[OCODE + ((size_t)b * NCB + i) * Tz + t0blk + wave * 2 + 1] = (float)k1;
        }

        // ---- loss term (one lane per column; z_e reconstructed as en*den) ----
        if (lane == 0) {
#pragma unroll
            for (int c = 0; c < 8; ++c) {
                float dd = en[0][c] * den0 - cq0[c];
                lsum = fmaf(dd, dd, lsum);
            }
        }
        if (lane == 1) {
#pragma unroll
            for (int c = 0; c < 8; ++c) {
                float dd = en[1][c] * den1 - cq1[c];
                lsum = fmaf(dd, dd, lsum);
            }
        }

        // ---- out_proj + residual update (w_out/b_out from global, coalesced) ----
        {
            const float* wo = w_out + (size_t)i * 4096 + (size_t)lane * 64;
            const float* bo = b_out + (size_t)i * Dz + lane * 8;
            float4 bA = *(const float4*)bo;
            float4 bB = *(const float4*)(bo + 4);
            float bv[8] = {bA.x, bA.y, bA.z, bA.w, bB.x, bB.y, bB.z, bB.w};
#pragma unroll
            for (int j = 0; j < 8; ++j) {
                float4 wa  = *(const float4*)(wo + j * 8);
                float4 wb2 = *(const float4*)(wo + j * 8 + 4);
                float s0 = wa.x * cq0[0];
                float s1 = wa.x * cq1[0];
                s0 = fmaf(wa.y,  cq0[1], s0); s1 = fmaf(wa.y,  cq1[1], s1);
                s0 = fmaf(wa.z,  cq0[2], s0); s1 = fmaf(wa.z,  cq1[2], s1);
                s0 = fmaf(wa.w,  cq0[3], s0); s1 = fmaf(wa.w,  cq1[3], s1);
                s0 = fmaf(wb2.x, cq0[4], s0); s1 = fmaf(wb2.x, cq1[4], s1);
                s0 = fmaf(wb2.y, cq0[5], s0); s1 = fmaf(wb2.y, cq1[5], s1);
                s0 = fmaf(wb2.z, cq0[6], s0); s1 = fmaf(wb2.z, cq1[6], s1);
                s0 = fmaf(wb2.w, cq0[7], s0); s1 = fmaf(wb2.w, cq1[7], s1);
                res2[0][j] -= (s0 + bv[j]);
                res2[1][j] -= (s1 + bv[j]);
            }
        }
    }

    // ---- z_q = z - residual_final : res -> LDS transpose, re-read z, store ----
    __syncthreads();   // all waves done with s_cbnT before s_tr reuse
#pragma unroll 1
    for (int c = 0; c < 4; ++c) {
        if ((lane >> 4) == c) {
            const int lr = (lane & 15) * 8;
#pragma unroll
            for (int col = 0; col < 2; ++col)
#pragma unroll
                for (int j = 0; j < 8; ++j)
                    s_tr[(wave * 2 + col) * 132 + lr + j] = res2[col][j];
        }
        __syncthreads();
        {
            const int r = tid >> 3;              // 0..127
            const int u = (tid & 7) * 4;
            float4 zv = *(const float4*)(z + zbase + (size_t)(c * 128 + r) * Tz + u);
            float4 v;
            v.x = zv.x - s_tr[(u + 0) * 132 + r];
            v.y = zv.y - s_tr[(u + 1) * 132 + r];
            v.z = zv.z - s_tr[(u + 2) * 132 + r];
            v.w = zv.w - s_tr[(u + 3) * 132 + r];
            *(float4*)(out + OZQ + zbase + (size_t)(c * 128 + r) * Tz + u) = v;
        }
        __syncthreads();
    }

    // ---- loss reduction (DPP, no DS shuffles) ----
    float lt = wave_sum64(lsum);
    if (lane == 0) s_red[wave] = lt;
    __syncthreads();
    if (tid == 0) {
        float t = 0.f;
#pragma unroll
        for (int w2 = 0; w2 < 16; ++w2) t += s_red[w2];
        t *= (1.f / 524288.f);   // /(16*8*4096)
        atomicAdd(&out[OCL], t);
        atomicAdd(&out[OCL + 1], t);
    }
}

// ---------------------------------------------------------------------------
extern "C" void kernel_launch(void* const* d_in, const int* in_sizes, int n_in,
                              void* d_out, int out_size, void* d_ws, size_t ws_size,
                              hipStream_t stream) {
    (void)in_sizes; (void)n_in; (void)out_size; (void)ws_size;
    const float* z     = (const float*)d_in[0];
    const float* w_in  = (const float*)d_in[1];
    const float* b_in  = (const float*)d_in[2];
    const float* w_out = (const float*)d_in[3];
    const float* b_out = (const float*)d_in[4];
    const float* cb    = (const float*)d_in[5];
    float* ws  = (float*)d_ws;
    float* out = (float*)d_out;

    rvq_prep<<<NCB, 1024, 0, stream>>>(cb, ws, out);
    rvq_main<<<2048, 1024, 0, stream>>>(z, w_in, b_in, w_out, b_out, cb, ws, out);
}

// Round 7
// 1347.759 us; speedup vs baseline: 1.1185x; 1.1185x over previous
//
#include <hip/hip_runtime.h>
#include <math.h>

// Problem constants
#define Bz  16
#define Dz  512
#define Tz  4096
#define NCB 9
#define Kz  1024
#define CD  8

// Output layout (floats): z_q | codes | latents | cl | cbl
static const unsigned long long OZQ   = 0ull;
static const unsigned long long OCODE = 33554432ull;             // 16*512*4096
static const unsigned long long OLAT  = 34144256ull;             // + 16*9*4096
static const unsigned long long OCL   = 38862848ull;             // + 16*72*4096

#define WS_CBN2_OFF (NCB * CD * Kz)   // ws: cbnT[9][8][1024] then cbn2[9][1024]

// ---------------------------------------------------------------------------
// Prep: normalized codebooks (transposed) + their squared norms; zero loss slots
// ---------------------------------------------------------------------------
__global__ __launch_bounds__(1024) void rvq_prep(const float* __restrict__ cb,
                                                 float* __restrict__ ws,
                                                 float* __restrict__ out) {
    const int i = blockIdx.x;    // codebook 0..8
    const int k = threadIdx.x;   // entry 0..1023
    const float* row = cb + ((size_t)i * Kz + k) * CD;
    float v[CD];
#pragma unroll
    for (int c = 0; c < CD; ++c) v[c] = row[c];
    float ss = 0.f;
#pragma unroll
    for (int c = 0; c < CD; ++c) ss += v[c] * v[c];
    const float den = fmaxf(sqrtf(ss), 1e-12f);   // F.normalize eps clamp
    float cb2 = 0.f;
#pragma unroll
    for (int c = 0; c < CD; ++c) {
        float e = v[c] / den;
        ws[((size_t)i * CD + c) * Kz + k] = e;     // cbnT[i][c][k]
        cb2 += e * e;
    }
    ws[WS_CBN2_OFF + (size_t)i * Kz + k] = cb2;
    if (i == 0 && k == 0) { out[OCL] = 0.f; out[OCL + 1] = 0.f; }
}

// ---------------------------------------------------------------------------
// DPP wave64 reductions — VALU only, keeps DS pipe free for data.
// ---------------------------------------------------------------------------
template <int CTRL>
__device__ __forceinline__ float dpp_add_t(float v) {
    int t = __builtin_amdgcn_update_dpp(0, __float_as_int(v), CTRL, 0xf, 0xf, true);
    return v + __int_as_float(t);
}
__device__ __forceinline__ float wave_sum64(float v) {
    v = dpp_add_t<0x111>(v);   // row_shr:1
    v = dpp_add_t<0x112>(v);   // row_shr:2
    v = dpp_add_t<0x114>(v);   // row_shr:4
    v = dpp_add_t<0x118>(v);   // row_shr:8
    v = dpp_add_t<0x142>(v);   // row_bcast:15
    v = dpp_add_t<0x143>(v);   // row_bcast:31
    return __int_as_float(__builtin_amdgcn_readlane(__float_as_int(v), 63));
}
template <int CTRL>
__device__ __forceinline__ float dpp_min_t(float v) {
    int t = __builtin_amdgcn_update_dpp(__float_as_int(v), __float_as_int(v),
                                        CTRL, 0xf, 0xf, false);
    return fminf(v, __int_as_float(t));
}
__device__ __forceinline__ float wave_min64(float v) {
    v = dpp_min_t<0x111>(v);
    v = dpp_min_t<0x112>(v);
    v = dpp_min_t<0x114>(v);
    v = dpp_min_t<0x118>(v);
    v = dpp_min_t<0x142>(v);
    v = dpp_min_t<0x143>(v);
    return __int_as_float(__builtin_amdgcn_readlane(__float_as_int(v), 63));
}
__device__ __forceinline__ float rfl(float v) {
    return __int_as_float(__builtin_amdgcn_readfirstlane(__float_as_int(v)));
}

// ---------------------------------------------------------------------------
// Main: 1024 threads = 16 waves; block covers 32 t-columns; wave owns 2 cols.
// Round-4 structure (ALL operands LDS-staged, latents/codes LDS-staged ->
// coalesced flush, no hot-loop global operand reads => no load-hoist spill)
// + round-6 conflict-free layouts:
//   s_w[c][512], s_woT[c][512]: lane reads 32B @ c*512+8*lane -> 2-way (free)
//   s_cbnT[c][1024], s_cbn2[1024]: lane owns k=mq*256+lane*4 -> 16B contig,
//   conflict-free. Reductions on VALU (DPP); winner rows readfirstlane->SGPR.
// LDS ~74 KB -> 2 blocks/CU = 32 waves/CU.
// ---------------------------------------------------------------------------
__global__ __launch_bounds__(1024)
void rvq_main(
    const float* __restrict__ z,
    const float* __restrict__ w_in,
    const float* __restrict__ b_in,
    const float* __restrict__ w_out,
    const float* __restrict__ b_out,
    const float* __restrict__ cb,
    const float* __restrict__ ws,
    float* __restrict__ out)
{
    __shared__ float s_w[CD * 512];     // 16 KB  w_in[c][d]
    __shared__ float s_woT[CD * 512];   // 16 KB  w_out^T[c][d]
    __shared__ float s_cbnT[CD * Kz];   // 32 KB  [c][k]
    __shared__ float s_cbn2[Kz];        //  4 KB
    __shared__ float s_bo[512];         //  2 KB
    __shared__ float s_lat[8 * 33];
    __shared__ float s_code[NCB * 32];
    __shared__ float s_red[16];
    float* s_tr = s_cbnT;               // alias: 32x132 transpose scratch

    const int tid  = threadIdx.x;
    const int wave = tid >> 6;                   // 0..15
    const int lane = tid & 63;
    const int bb   = blockIdx.x;                 // 0..2047
    const int b    = bb >> 7;                    // batch
    const int t0blk = (bb & 127) << 5;           // block's 32-column base

    const size_t zbase = (size_t)b * Dz * Tz + t0blk;

    // ---- coalesced z load -> LDS transpose -> registers (into res2) ----
    float res2[2][8];
#pragma unroll 1
    for (int c = 0; c < 4; ++c) {
        {
            const int r = tid >> 3;              // 0..127
            const int u = (tid & 7) * 4;         // 0..28
            float4 v = *(const float4*)(z + zbase + (size_t)(c * 128 + r) * Tz + u);
            s_tr[(u + 0) * 132 + r] = v.x;
            s_tr[(u + 1) * 132 + r] = v.y;
            s_tr[(u + 2) * 132 + r] = v.z;
            s_tr[(u + 3) * 132 + r] = v.w;
        }
        __syncthreads();
        if ((lane >> 4) == c) {
            const int lr = (lane & 15) * 8;
#pragma unroll
            for (int col = 0; col < 2; ++col)
#pragma unroll
                for (int j = 0; j < 8; ++j)
                    res2[col][j] = s_tr[(wave * 2 + col) * 132 + lr + j];
        }
        __syncthreads();
    }

    float lsum = 0.f;

#pragma unroll 1
    for (int i = 0; i < NCB; ++i) {
        __syncthreads();   // prev step's LDS reads done
        // ---- flush previous step's latents (coalesced 128B rows) ----
        if (i > 0 && tid < 256) {
            const int c2 = tid >> 5, u = tid & 31;
            out[OLAT + ((size_t)b * 72 + (i - 1) * 8 + c2) * Tz + t0blk + u] =
                s_lat[c2 * 33 + u];
        }
        // ---- stage all step-i operands into LDS (conflict-free layouts) ----
        {
            // w_in[c][d] is row-major [8][512] -> straight copy
            ((float4*)s_w)[tid] = ((const float4*)(w_in + (size_t)i * 4096))[tid];
            // w_out [512][8] -> transposed into s_woT[c][d]
            float4 v = ((const float4*)(w_out + (size_t)i * 4096))[tid];
            const int d = tid >> 1, c0 = (tid & 1) * 4;
            s_woT[(c0 + 0) * 512 + d] = v.x;
            s_woT[(c0 + 1) * 512 + d] = v.y;
            s_woT[(c0 + 2) * 512 + d] = v.z;
            s_woT[(c0 + 3) * 512 + d] = v.w;
            // cbnT plain copy
            const float4* srcT = (const float4*)(ws + (size_t)i * 8192);
            ((float4*)s_cbnT)[tid]        = srcT[tid];
            ((float4*)s_cbnT)[tid + 1024] = srcT[tid + 1024];
            if (tid < 256)
                ((float4*)s_cbn2)[tid] =
                    ((const float4*)(ws + WS_CBN2_OFF + (size_t)i * Kz))[tid];
            if (tid < 128)
                ((float4*)s_bo)[tid] = ((const float4*)(b_out + (size_t)i * Dz))[tid];
        }
        __syncthreads();

        // ---- z_e = w_in @ residual + b_in : DPP sums -> uniform scalars ----
        float zz[2][8];
#pragma unroll
        for (int c = 0; c < 8; ++c) {
            float4 wa = *(const float4*)&s_w[c * 512 + lane * 8];
            float4 wc = *(const float4*)&s_w[c * 512 + lane * 8 + 4];
            float q0 = wa.x * res2[0][0];
            float q1 = wa.x * res2[1][0];
            q0 = fmaf(wa.y, res2[0][1], q0); q1 = fmaf(wa.y, res2[1][1], q1);
            q0 = fmaf(wa.z, res2[0][2], q0); q1 = fmaf(wa.z, res2[1][2], q1);
            q0 = fmaf(wa.w, res2[0][3], q0); q1 = fmaf(wa.w, res2[1][3], q1);
            q0 = fmaf(wc.x, res2[0][4], q0); q1 = fmaf(wc.x, res2[1][4], q1);
            q0 = fmaf(wc.y, res2[0][5], q0); q1 = fmaf(wc.y, res2[1][5], q1);
            q0 = fmaf(wc.z, res2[0][6], q0); q1 = fmaf(wc.z, res2[1][6], q1);
            q0 = fmaf(wc.w, res2[0][7], q0); q1 = fmaf(wc.w, res2[1][7], q1);
            zz[0][c] = wave_sum64(q0);
            zz[1][c] = wave_sum64(q1);
        }
        {
            float4 bA = *(const float4*)(b_in + i * 8);
            float4 bB = *(const float4*)(b_in + i * 8 + 4);
            zz[0][0] += bA.x; zz[1][0] += bA.x;
            zz[0][1] += bA.y; zz[1][1] += bA.y;
            zz[0][2] += bA.z; zz[1][2] += bA.z;
            zz[0][3] += bA.w; zz[1][3] += bA.w;
            zz[0][4] += bB.x; zz[1][4] += bB.x;
            zz[0][5] += bB.y; zz[1][5] += bB.y;
            zz[0][6] += bB.z; zz[1][6] += bB.z;
            zz[0][7] += bB.w; zz[1][7] += bB.w;
        }

        // ---- latents stage to LDS (flushed next iteration) ----
        {
            float v = zz[0][0];
            v = (lane == 1)  ? zz[1][0] : v;
            v = (lane == 2)  ? zz[0][1] : v;
            v = (lane == 3)  ? zz[1][1] : v;
            v = (lane == 4)  ? zz[0][2] : v;
            v = (lane == 5)  ? zz[1][2] : v;
            v = (lane == 6)  ? zz[0][3] : v;
            v = (lane == 7)  ? zz[1][3] : v;
            v = (lane == 8)  ? zz[0][4] : v;
            v = (lane == 9)  ? zz[1][4] : v;
            v = (lane == 10) ? zz[0][5] : v;
            v = (lane == 11) ? zz[1][5] : v;
            v = (lane == 12) ? zz[0][6] : v;
            v = (lane == 13) ? zz[1][6] : v;
            v = (lane == 14) ? zz[0][7] : v;
            v = (lane == 15) ? zz[1][7] : v;
            if (lane < 16)
                s_lat[(lane >> 1) * 33 + wave * 2 + (lane & 1)] = v;
        }

        // ---- l2-normalize (uniform) ----
        float ss0 = 0.f, ss1 = 0.f;
#pragma unroll
        for (int c = 0; c < 8; ++c) {
            ss0 = fmaf(zz[0][c], zz[0][c], ss0);
            ss1 = fmaf(zz[1][c], zz[1][c], ss1);
        }
        const float den0 = fmaxf(sqrtf(ss0), 1e-12f);
        const float den1 = fmaxf(sqrtf(ss1), 1e-12f);
        float en[2][8];
#pragma unroll
        for (int c = 0; c < 8; ++c) {
            en[0][c] = zz[0][c] / den0;
            en[1][c] = zz[1][c] / den1;
        }

        // ---- distance scoring: lane owns k = mq*256 + lane*4 + q ----
        float best0 = 1e30f, best1 = 1e30f;
        int   bi0 = 0, bi1 = 0;
#pragma unroll
        for (int mq = 0; mq < 4; ++mq) {
            const int kb = mq * 256 + lane * 4;
            float4 c2 = *(const float4*)&s_cbn2[kb];
            float d00 = 0.f, d01 = 0.f, d02 = 0.f, d03 = 0.f;
            float d10 = 0.f, d11 = 0.f, d12 = 0.f, d13 = 0.f;
#pragma unroll
            for (int c = 0; c < 8; ++c) {
                float4 v = *(const float4*)&s_cbnT[c * 1024 + kb];
                d00 = fmaf(en[0][c], v.x, d00); d10 = fmaf(en[1][c], v.x, d10);
                d01 = fmaf(en[0][c], v.y, d01); d11 = fmaf(en[1][c], v.y, d11);
                d02 = fmaf(en[0][c], v.z, d02); d12 = fmaf(en[1][c], v.z, d12);
                d03 = fmaf(en[0][c], v.w, d03); d13 = fmaf(en[1][c], v.w, d13);
            }
            float dist;
            dist = fmaf(-2.f, d00, c2.x); if (dist < best0) { best0 = dist; bi0 = kb + 0; }
            dist = fmaf(-2.f, d01, c2.y); if (dist < best0) { best0 = dist; bi0 = kb + 1; }
            dist = fmaf(-2.f, d02, c2.z); if (dist < best0) { best0 = dist; bi0 = kb + 2; }
            dist = fmaf(-2.f, d03, c2.w); if (dist < best0) { best0 = dist; bi0 = kb + 3; }
            dist = fmaf(-2.f, d10, c2.x); if (dist < best1) { best1 = dist; bi1 = kb + 0; }
            dist = fmaf(-2.f, d11, c2.y); if (dist < best1) { best1 = dist; bi1 = kb + 1; }
            dist = fmaf(-2.f, d12, c2.z); if (dist < best1) { best1 = dist; bi1 = kb + 2; }
            dist = fmaf(-2.f, d13, c2.w); if (dist < best1) { best1 = dist; bi1 = kb + 3; }
        }
        // wave argmin: DPP min + ballot + readlane -> uniform winner index
        const float g0 = wave_min64(best0);
        const float g1 = wave_min64(best1);
        const int wl0 = __ffsll((long long)(unsigned long long)__ballot(best0 == g0)) - 1;
        const int wl1 = __ffsll((long long)(unsigned long long)__ballot(best1 == g1)) - 1;
        const int k0 = __builtin_amdgcn_readlane(bi0, wl0);
        const int k1 = __builtin_amdgcn_readlane(bi1, wl1);

        // ---- fetch raw codebook rows (uniform addr; pin to SGPRs via RFL) ----
        float cq0[8], cq1[8];
        {
            const float* cr0 = cb + ((size_t)i * Kz + k0) * CD;
            float4 qa = *(const float4*)cr0, qb = *(const float4*)(cr0 + 4);
            cq0[0] = rfl(qa.x); cq0[1] = rfl(qa.y); cq0[2] = rfl(qa.z); cq0[3] = rfl(qa.w);
            cq0[4] = rfl(qb.x); cq0[5] = rfl(qb.y); cq0[6] = rfl(qb.z); cq0[7] = rfl(qb.w);
            const float* cr1 = cb + ((size_t)i * Kz + k1) * CD;
            float4 qc = *(const float4*)cr1, qd = *(const float4*)(cr1 + 4);
            cq1[0] = rfl(qc.x); cq1[1] = rfl(qc.y); cq1[2] = rfl(qc.z); cq1[3] = rfl(qc.w);
            cq1[4] = rfl(qd.x); cq1[5] = rfl(qd.y); cq1[6] = rfl(qd.z); cq1[7] = rfl(qd.w);
        }

        // ---- codes stage to LDS ----
        if (lane < 2)
            s_code[i * 32 + wave * 2 + lane] = (lane == 0) ? (float)k0 : (float)k1;

        // ---- loss term (one lane per column; values uniform) ----
        if (lane == 0) {
#pragma unroll
            for (int c = 0; c < 8; ++c) {
                float dd = zz[0][c] - cq0[c];
                lsum = fmaf(dd, dd, lsum);
            }
        }
        if (lane == 1) {
#pragma unroll
            for (int c = 0; c < 8; ++c) {
                float dd = zz[1][c] - cq1[c];
                lsum = fmaf(dd, dd, lsum);
            }
        }

        // ---- out_proj + residual update, c-major (reads s_woT like s_w) ----
#pragma unroll
        for (int c = 0; c < 8; ++c) {
            float4 wa = *(const float4*)&s_woT[c * 512 + lane * 8];
            float4 wc = *(const float4*)&s_woT[c * 512 + lane * 8 + 4];
            const float a0 = cq0[c], a1 = cq1[c];
            res2[0][0] = fmaf(-a0, wa.x, res2[0][0]); res2[1][0] = fmaf(-a1, wa.x, res2[1][0]);
            res2[0][1] = fmaf(-a0, wa.y, res2[0][1]); res2[1][1] = fmaf(-a1, wa.y, res2[1][1]);
            res2[0][2] = fmaf(-a0, wa.z, res2[0][2]); res2[1][2] = fmaf(-a1, wa.z, res2[1][2]);
            res2[0][3] = fmaf(-a0, wa.w, res2[0][3]); res2[1][3] = fmaf(-a1, wa.w, res2[1][3]);
            res2[0][4] = fmaf(-a0, wc.x, res2[0][4]); res2[1][4] = fmaf(-a1, wc.x, res2[1][4]);
            res2[0][5] = fmaf(-a0, wc.y, res2[0][5]); res2[1][5] = fmaf(-a1, wc.y, res2[1][5]);
            res2[0][6] = fmaf(-a0, wc.z, res2[0][6]); res2[1][6] = fmaf(-a1, wc.z, res2[1][6]);
            res2[0][7] = fmaf(-a0, wc.w, res2[0][7]); res2[1][7] = fmaf(-a1, wc.w, res2[1][7]);
        }
        {
            float4 bA = *(const float4*)&s_bo[lane * 8];
            float4 bB = *(const float4*)&s_bo[lane * 8 + 4];
            res2[0][0] -= bA.x; res2[1][0] -= bA.x;
            res2[0][1] -= bA.y; res2[1][1] -= bA.y;
            res2[0][2] -= bA.z; res2[1][2] -= bA.z;
            res2[0][3] -= bA.w; res2[1][3] -= bA.w;
            res2[0][4] -= bB.x; res2[1][4] -= bB.x;
            res2[0][5] -= bB.y; res2[1][5] -= bB.y;
            res2[0][6] -= bB.z; res2[1][6] -= bB.z;
            res2[0][7] -= bB.w; res2[1][7] -= bB.w;
        }
    }

    // ---- flush last step's latents + all codes (coalesced) ----
    __syncthreads();
    if (tid < 256) {
        const int c2 = tid >> 5, u = tid & 31;
        out[OLAT + ((size_t)b * 72 + 8 * 8 + c2) * Tz + t0blk + u] = s_lat[c2 * 33 + u];
    }
    if (tid < NCB * 32) {
        const int i2 = tid >> 5, u = tid & 31;
        out[OCODE + ((size_t)b * NCB + i2) * Tz + t0blk + u] = s_code[i2 * 32 + u];
    }

    // ---- z_q = z - residual_final : res -> LDS transpose, re-read z, store ----
#pragma unroll 1
    for (int c = 0; c < 4; ++c) {
        if ((lane >> 4) == c) {
            const int lr = (lane & 15) * 8;
#pragma unroll
            for (int col = 0; col < 2; ++col)
#pragma unroll
                for (int j = 0; j < 8; ++j)
                    s_tr[(wave * 2 + col) * 132 + lr + j] = res2[col][j];
        }
        __syncthreads();
        {
            const int r = tid >> 3;              // 0..127
            const int u = (tid & 7) * 4;
            float4 zv = *(const float4*)(z + zbase + (size_t)(c * 128 + r) * Tz + u);
            float4 v;
            v.x = zv.x - s_tr[(u + 0) * 132 + r];
            v.y = zv.y - s_tr[(u + 1) * 132 + r];
            v.z = zv.z - s_tr[(u + 2) * 132 + r];
            v.w = zv.w - s_tr[(u + 3) * 132 + r];
            *(float4*)(out + OZQ + zbase + (size_t)(c * 128 + r) * Tz + u) = v;
        }
        __syncthreads();
    }

    // ---- loss reduction (DPP) ----
    float lt = wave_sum64(lsum);
    if (lane == 0) s_red[wave] = lt;
    __syncthreads();
    if (tid == 0) {
        float t = 0.f;
#pragma unroll
        for (int w2 = 0; w2 < 16; ++w2) t += s_red[w2];
        t *= (1.f / 524288.f);   // /(16*8*4096)
        atomicAdd(&out[OCL], t);
        atomicAdd(&out[OCL + 1], t);
    }
}

// ---------------------------------------------------------------------------
extern "C" void kernel_launch(void* const* d_in, const int* in_sizes, int n_in,
                              void* d_out, int out_size, void* d_ws, size_t ws_size,
                              hipStream_t stream) {
    (void)in_sizes; (void)n_in; (void)out_size; (void)ws_size;
    const float* z     = (const float*)d_in[0];
    const float* w_in  = (const float*)d_in[1];
    const float* b_in  = (const float*)d_in[2];
    const float* w_out = (const float*)d_in[3];
    const float* b_out = (const float*)d_in[4];
    const float* cb    = (const float*)d_in[5];
    float* ws  = (float*)d_ws;
    float* out = (float*)d_out;

    rvq_prep<<<NCB, 1024, 0, stream>>>(cb, ws, out);
    rvq_main<<<2048, 1024, 0, stream>>>(z, w_in, b_in, w_out, b_out, cb, ws, out);
}

// Round 8
// 1186.026 us; speedup vs baseline: 1.2711x; 1.1364x over previous
//
#include <hip/hip_runtime.h>
#include <math.h>

// Problem constants
#define Bz  16
#define Dz  512
#define Tz  4096
#define NCB 9
#define Kz  1024
#define CD  8

// Output layout (floats): z_q | codes | latents | cl | cbl
static const unsigned long long OZQ   = 0ull;
static const unsigned long long OCODE = 33554432ull;             // 16*512*4096
static const unsigned long long OLAT  = 34144256ull;             // + 16*9*4096
static const unsigned long long OCL   = 38862848ull;             // + 16*72*4096

#define WS_CBN2_OFF (NCB * CD * Kz)   // ws: cbnT[9][8][1024] then cbn2[9][1024]

// ---------------------------------------------------------------------------
// Prep: normalized codebooks (transposed) + their squared norms; zero loss slots
// ---------------------------------------------------------------------------
__global__ __launch_bounds__(1024) void rvq_prep(const float* __restrict__ cb,
                                                 float* __restrict__ ws,
                                                 float* __restrict__ out) {
    const int i = blockIdx.x;    // codebook 0..8
    const int k = threadIdx.x;   // entry 0..1023
    const float* row = cb + ((size_t)i * Kz + k) * CD;
    float v[CD];
#pragma unroll
    for (int c = 0; c < CD; ++c) v[c] = row[c];
    float ss = 0.f;
#pragma unroll
    for (int c = 0; c < CD; ++c) ss += v[c] * v[c];
    const float den = fmaxf(sqrtf(ss), 1e-12f);   // F.normalize eps clamp
    float cb2 = 0.f;
#pragma unroll
    for (int c = 0; c < CD; ++c) {
        float e = v[c] / den;
        ws[((size_t)i * CD + c) * Kz + k] = e;     // cbnT[i][c][k]
        cb2 += e * e;
    }
    ws[WS_CBN2_OFF + (size_t)i * Kz + k] = cb2;
    if (i == 0 && k == 0) { out[OCL] = 0.f; out[OCL + 1] = 0.f; }
}

// ---------------------------------------------------------------------------
// DPP wave64 reductions — VALU only, keeps DS pipe free for data.
// ---------------------------------------------------------------------------
template <int CTRL>
__device__ __forceinline__ float dpp_add_t(float v) {
    int t = __builtin_amdgcn_update_dpp(0, __float_as_int(v), CTRL, 0xf, 0xf, true);
    return v + __int_as_float(t);
}
__device__ __forceinline__ float wave_sum64(float v) {
    v = dpp_add_t<0x111>(v);   // row_shr:1
    v = dpp_add_t<0x112>(v);   // row_shr:2
    v = dpp_add_t<0x114>(v);   // row_shr:4
    v = dpp_add_t<0x118>(v);   // row_shr:8
    v = dpp_add_t<0x142>(v);   // row_bcast:15
    v = dpp_add_t<0x143>(v);   // row_bcast:31
    return __int_as_float(__builtin_amdgcn_readlane(__float_as_int(v), 63));
}
template <int CTRL>
__device__ __forceinline__ float dpp_min_t(float v) {
    int t = __builtin_amdgcn_update_dpp(__float_as_int(v), __float_as_int(v),
                                        CTRL, 0xf, 0xf, false);
    return fminf(v, __int_as_float(t));
}
__device__ __forceinline__ float wave_min64(float v) {
    v = dpp_min_t<0x111>(v);
    v = dpp_min_t<0x112>(v);
    v = dpp_min_t<0x114>(v);
    v = dpp_min_t<0x118>(v);
    v = dpp_min_t<0x142>(v);
    v = dpp_min_t<0x143>(v);
    return __int_as_float(__builtin_amdgcn_readlane(__float_as_int(v), 63));
}
__device__ __forceinline__ float rfl(float v) {
    return __int_as_float(__builtin_amdgcn_readfirstlane(__float_as_int(v)));
}

// ---------------------------------------------------------------------------
// Main: 512 threads = 8 waves; block covers 16 t-columns; wave owns 2 cols.
// 512-thr blocks -> TWO resident blocks/CU (proven r0-r3) = two independent
// barrier domains: one block's staging drain hides under the other's compute.
// All operand reads conflict-free:
//   s_w / s_woT: [c][512] with slot-XOR swizzle s^=(s>>3)&1 (bit0^bit3 at
//     float4-slot level) -> each b128 read covers all 32 banks (8 acc/bank).
//   s_cbnT [c][1024], s_cbn2: lane owns k=mq*256+lane*4 -> 16B contiguous.
// Reductions on VALU (DPP); winner rows pinned uniform via readfirstlane.
// LDS ~72.8 KB -> 2 blocks/CU.
// ---------------------------------------------------------------------------
__global__ __launch_bounds__(512)
void rvq_main(
    const float* __restrict__ z,
    const float* __restrict__ w_in,
    const float* __restrict__ b_in,
    const float* __restrict__ w_out,
    const float* __restrict__ b_out,
    const float* __restrict__ cb,
    const float* __restrict__ ws,
    float* __restrict__ out)
{
    __shared__ float s_w[CD * 512];     // 16 KB  w_in[c][d] (slot-swizzled)
    __shared__ float s_woT[CD * 512];   // 16 KB  w_out^T[c][d] (slot-swizzled)
    __shared__ float s_cbnT[CD * Kz];   // 32 KB  [c][k]
    __shared__ float s_cbn2[Kz];        //  4 KB
    __shared__ float s_bo[512];         //  2 KB
    __shared__ float s_lat[8 * 17];     // per-step latents stage (16 cols)
    __shared__ float s_code[NCB * 16];  // codes stage
    __shared__ float s_red[8];
    float* s_tr = s_cbnT;               // alias: 16 cols x 132-stride transpose

    const int tid  = threadIdx.x;
    const int wave = tid >> 6;                   // 0..7
    const int lane = tid & 63;
    const int bb   = blockIdx.x;                 // 0..4095
    const int b    = bb >> 8;                    // batch
    const int t0blk = (bb & 255) << 4;           // block's 16-column base

    const size_t zbase = (size_t)b * Dz * Tz + t0blk;
    const int sw = (lane >> 2) & 1;              // read-side slot swizzle bit

    // ---- coalesced z load -> LDS transpose -> registers (into res2) ----
    // 4 chunks of 128 d-rows x 16 cols. Thread: r=tid>>2 (0..127), u=(tid&3)*4.
    float res2[2][8];
#pragma unroll 1
    for (int c = 0; c < 4; ++c) {
        {
            const int r = tid >> 2;              // 0..127
            const int u = (tid & 3) * 4;         // 0,4,8,12
            float4 v = *(const float4*)(z + zbase + (size_t)(c * 128 + r) * Tz + u);
            s_tr[(u + 0) * 132 + r] = v.x;
            s_tr[(u + 1) * 132 + r] = v.y;
            s_tr[(u + 2) * 132 + r] = v.z;
            s_tr[(u + 3) * 132 + r] = v.w;
        }
        __syncthreads();
        if ((lane >> 4) == c) {
            const int lr = (lane & 15) * 8;
#pragma unroll
            for (int col = 0; col < 2; ++col)
#pragma unroll
                for (int j = 0; j < 8; ++j)
                    res2[col][j] = s_tr[(wave * 2 + col) * 132 + lr + j];
        }
        __syncthreads();
    }

    float lsum = 0.f;

#pragma unroll 1
    for (int i = 0; i < NCB; ++i) {
        __syncthreads();   // prev step's LDS reads done
        // ---- flush previous step's latents (coalesced 64B rows) ----
        if (i > 0 && tid < 128) {
            const int c2 = tid >> 4, u = tid & 15;
            out[OLAT + ((size_t)b * 72 + (i - 1) * 8 + c2) * Tz + t0blk + u] =
                s_lat[c2 * 17 + u];
        }
        // ---- stage all step-i operands into LDS ----
        {
            // cbnT: 2048 f4 / 512 thr = 4 each (linear, conflict-free)
            const float4* srcT = (const float4*)(ws + (size_t)i * 8192);
#pragma unroll
            for (int it = 0; it < 4; ++it)
                ((float4*)s_cbnT)[tid + it * 512] = srcT[tid + it * 512];
            if (tid < 256)
                ((float4*)s_cbn2)[tid] =
                    ((const float4*)(ws + WS_CBN2_OFF + (size_t)i * Kz))[tid];
            // w_in: slot-swizzled store (s ^ ((s>>3)&1))
            const float4* srcW = (const float4*)(w_in + (size_t)i * 4096);
#pragma unroll
            for (int it = 0; it < 2; ++it) {
                const int s = tid + it * 512;
                ((float4*)s_w)[s ^ ((s >> 3) & 1)] = srcW[s];
            }
            // w_out [512][8] -> transposed + row-swizzled into s_woT[c][dsw]
            const float4* srcO = (const float4*)(w_out + (size_t)i * 4096);
#pragma unroll
            for (int it = 0; it < 2; ++it) {
                const int e4 = tid + it * 512;
                float4 v = srcO[e4];
                const int d = e4 >> 1, c0 = (e4 & 1) * 4;
                const int dsw = d ^ (((d >> 5) & 1) << 2);
                s_woT[(c0 + 0) * 512 + dsw] = v.x;
                s_woT[(c0 + 1) * 512 + dsw] = v.y;
                s_woT[(c0 + 2) * 512 + dsw] = v.z;
                s_woT[(c0 + 3) * 512 + dsw] = v.w;
            }
            if (tid < 128)
                ((float4*)s_bo)[tid] = ((const float4*)(b_out + (size_t)i * Dz))[tid];
        }
        __syncthreads();

        // ---- z_e = w_in @ residual + b_in : DPP sums -> uniform scalars ----
        float den0, den1;
        float en[2][8];
        {
            float zz[2][8];
#pragma unroll
            for (int c = 0; c < 8; ++c) {
                const int s0 = c * 128 + lane * 2;
                float4 wa = ((const float4*)s_w)[s0 + sw];
                float4 wc = ((const float4*)s_w)[s0 + 1 - sw];
                float q0 = wa.x * res2[0][0];
                float q1 = wa.x * res2[1][0];
                q0 = fmaf(wa.y, res2[0][1], q0); q1 = fmaf(wa.y, res2[1][1], q1);
                q0 = fmaf(wa.z, res2[0][2], q0); q1 = fmaf(wa.z, res2[1][2], q1);
                q0 = fmaf(wa.w, res2[0][3], q0); q1 = fmaf(wa.w, res2[1][3], q1);
                q0 = fmaf(wc.x, res2[0][4], q0); q1 = fmaf(wc.x, res2[1][4], q1);
                q0 = fmaf(wc.y, res2[0][5], q0); q1 = fmaf(wc.y, res2[1][5], q1);
                q0 = fmaf(wc.z, res2[0][6], q0); q1 = fmaf(wc.z, res2[1][6], q1);
                q0 = fmaf(wc.w, res2[0][7], q0); q1 = fmaf(wc.w, res2[1][7], q1);
                zz[0][c] = wave_sum64(q0);
                zz[1][c] = wave_sum64(q1);
            }
            float4 bA = *(const float4*)(b_in + i * 8);
            float4 bB = *(const float4*)(b_in + i * 8 + 4);
            zz[0][0] += bA.x; zz[1][0] += bA.x;
            zz[0][1] += bA.y; zz[1][1] += bA.y;
            zz[0][2] += bA.z; zz[1][2] += bA.z;
            zz[0][3] += bA.w; zz[1][3] += bA.w;
            zz[0][4] += bB.x; zz[1][4] += bB.x;
            zz[0][5] += bB.y; zz[1][5] += bB.y;
            zz[0][6] += bB.z; zz[1][6] += bB.z;
            zz[0][7] += bB.w; zz[1][7] += bB.w;

            // latents stage to LDS (flushed next iteration)
            float v = zz[0][0];
            v = (lane == 1)  ? zz[1][0] : v;
            v = (lane == 2)  ? zz[0][1] : v;
            v = (lane == 3)  ? zz[1][1] : v;
            v = (lane == 4)  ? zz[0][2] : v;
            v = (lane == 5)  ? zz[1][2] : v;
            v = (lane == 6)  ? zz[0][3] : v;
            v = (lane == 7)  ? zz[1][3] : v;
            v = (lane == 8)  ? zz[0][4] : v;
            v = (lane == 9)  ? zz[1][4] : v;
            v = (lane == 10) ? zz[0][5] : v;
            v = (lane == 11) ? zz[1][5] : v;
            v = (lane == 12) ? zz[0][6] : v;
            v = (lane == 13) ? zz[1][6] : v;
            v = (lane == 14) ? zz[0][7] : v;
            v = (lane == 15) ? zz[1][7] : v;
            if (lane < 16)
                s_lat[(lane >> 1) * 17 + wave * 2 + (lane & 1)] = v;

            // l2-normalize; zz dies here (loss later uses en*den)
            float ss0 = 0.f, ss1 = 0.f;
#pragma unroll
            for (int c = 0; c < 8; ++c) {
                ss0 = fmaf(zz[0][c], zz[0][c], ss0);
                ss1 = fmaf(zz[1][c], zz[1][c], ss1);
            }
            den0 = fmaxf(sqrtf(ss0), 1e-12f);
            den1 = fmaxf(sqrtf(ss1), 1e-12f);
#pragma unroll
            for (int c = 0; c < 8; ++c) {
                en[0][c] = zz[0][c] / den0;
                en[1][c] = zz[1][c] / den1;
            }
        }

        // ---- distance scoring: lane owns k = mq*256 + lane*4 + q ----
        float best0 = 1e30f, best1 = 1e30f;
        int   bi0 = 0, bi1 = 0;
#pragma unroll
        for (int mq = 0; mq < 4; ++mq) {
            const int kb = mq * 256 + lane * 4;
            float4 c2 = *(const float4*)&s_cbn2[kb];
            float d00 = 0.f, d01 = 0.f, d02 = 0.f, d03 = 0.f;
            float d10 = 0.f, d11 = 0.f, d12 = 0.f, d13 = 0.f;
#pragma unroll
            for (int c = 0; c < 8; ++c) {
                float4 v = *(const float4*)&s_cbnT[c * 1024 + kb];
                d00 = fmaf(en[0][c], v.x, d00); d10 = fmaf(en[1][c], v.x, d10);
                d01 = fmaf(en[0][c], v.y, d01); d11 = fmaf(en[1][c], v.y, d11);
                d02 = fmaf(en[0][c], v.z, d02); d12 = fmaf(en[1][c], v.z, d12);
                d03 = fmaf(en[0][c], v.w, d03); d13 = fmaf(en[1][c], v.w, d13);
            }
            float dist;
            dist = fmaf(-2.f, d00, c2.x); if (dist < best0) { best0 = dist; bi0 = kb + 0; }
            dist = fmaf(-2.f, d01, c2.y); if (dist < best0) { best0 = dist; bi0 = kb + 1; }
            dist = fmaf(-2.f, d02, c2.z); if (dist < best0) { best0 = dist; bi0 = kb + 2; }
            dist = fmaf(-2.f, d03, c2.w); if (dist < best0) { best0 = dist; bi0 = kb + 3; }
            dist = fmaf(-2.f, d10, c2.x); if (dist < best1) { best1 = dist; bi1 = kb + 0; }
            dist = fmaf(-2.f, d11, c2.y); if (dist < best1) { best1 = dist; bi1 = kb + 1; }
            dist = fmaf(-2.f, d12, c2.z); if (dist < best1) { best1 = dist; bi1 = kb + 2; }
            dist = fmaf(-2.f, d13, c2.w); if (dist < best1) { best1 = dist; bi1 = kb + 3; }
        }
        // wave argmin: DPP min + ballot + readlane -> uniform winner index
        const float g0 = wave_min64(best0);
        const float g1 = wave_min64(best1);
        const int wl0 = __ffsll((long long)(unsigned long long)__ballot(best0 == g0)) - 1;
        const int wl1 = __ffsll((long long)(unsigned long long)__ballot(best1 == g1)) - 1;
        const int k0 = __builtin_amdgcn_readlane(bi0, wl0);
        const int k1 = __builtin_amdgcn_readlane(bi1, wl1);

        // ---- fetch raw codebook rows (uniform addr; pin uniform via RFL) ----
        float cq0[8], cq1[8];
        {
            const float* cr0 = cb + ((size_t)i * Kz + k0) * CD;
            float4 qa = *(const float4*)cr0, qb = *(const float4*)(cr0 + 4);
            cq0[0] = rfl(qa.x); cq0[1] = rfl(qa.y); cq0[2] = rfl(qa.z); cq0[3] = rfl(qa.w);
            cq0[4] = rfl(qb.x); cq0[5] = rfl(qb.y); cq0[6] = rfl(qb.z); cq0[7] = rfl(qb.w);
            const float* cr1 = cb + ((size_t)i * Kz + k1) * CD;
            float4 qc = *(const float4*)cr1, qd = *(const float4*)(cr1 + 4);
            cq1[0] = rfl(qc.x); cq1[1] = rfl(qc.y); cq1[2] = rfl(qc.z); cq1[3] = rfl(qc.w);
            cq1[4] = rfl(qd.x); cq1[5] = rfl(qd.y); cq1[6] = rfl(qd.z); cq1[7] = rfl(qd.w);
        }

        // ---- codes stage to LDS ----
        if (lane < 2)
            s_code[i * 16 + wave * 2 + lane] = (lane == 0) ? (float)k0 : (float)k1;

        // ---- loss term (z_e reconstructed as en*den; one lane per column) ----
        if (lane == 0) {
#pragma unroll
            for (int c = 0; c < 8; ++c) {
                float dd = en[0][c] * den0 - cq0[c];
                lsum = fmaf(dd, dd, lsum);
            }
        }
        if (lane == 1) {
#pragma unroll
            for (int c = 0; c < 8; ++c) {
                float dd = en[1][c] * den1 - cq1[c];
                lsum = fmaf(dd, dd, lsum);
            }
        }

        // ---- out_proj + residual update, c-major swizzled s_woT reads ----
#pragma unroll
        for (int c = 0; c < 8; ++c) {
            const int s0 = c * 128 + lane * 2;
            float4 wa = ((const float4*)s_woT)[s0 + sw];
            float4 wc = ((const float4*)s_woT)[s0 + 1 - sw];
            const float a0 = cq0[c], a1 = cq1[c];
            res2[0][0] = fmaf(-a0, wa.x, res2[0][0]); res2[1][0] = fmaf(-a1, wa.x, res2[1][0]);
            res2[0][1] = fmaf(-a0, wa.y, res2[0][1]); res2[1][1] = fmaf(-a1, wa.y, res2[1][1]);
            res2[0][2] = fmaf(-a0, wa.z, res2[0][2]); res2[1][2] = fmaf(-a1, wa.z, res2[1][2]);
            res2[0][3] = fmaf(-a0, wa.w, res2[0][3]); res2[1][3] = fmaf(-a1, wa.w, res2[1][3]);
            res2[0][4] = fmaf(-a0, wc.x, res2[0][4]); res2[1][4] = fmaf(-a1, wc.x, res2[1][4]);
            res2[0][5] = fmaf(-a0, wc.y, res2[0][5]); res2[1][5] = fmaf(-a1, wc.y, res2[1][5]);
            res2[0][6] = fmaf(-a0, wc.z, res2[0][6]); res2[1][6] = fmaf(-a1, wc.z, res2[1][6]);
            res2[0][7] = fmaf(-a0, wc.w, res2[0][7]); res2[1][7] = fmaf(-a1, wc.w, res2[1][7]);
        }
        {
            float4 bA = *(const float4*)&s_bo[lane * 8];
            float4 bB = *(const float4*)&s_bo[lane * 8 + 4];
            res2[0][0] -= bA.x; res2[1][0] -= bA.x;
            res2[0][1] -= bA.y; res2[1][1] -= bA.y;
            res2[0][2] -= bA.z; res2[1][2] -= bA.z;
            res2[0][3] -= bA.w; res2[1][3] -= bA.w;
            res2[0][4] -= bB.x; res2[1][4] -= bB.x;
            res2[0][5] -= bB.y; res2[1][5] -= bB.y;
            res2[0][6] -= bB.z; res2[1][6] -= bB.z;
            res2[0][7] -= bB.w; res2[1][7] -= bB.w;
        }
    }

    // ---- flush last step's latents + all codes ----
    __syncthreads();
    if (tid < 128) {
        const int c2 = tid >> 4, u = tid & 15;
        out[OLAT + ((size_t)b * 72 + 8 * 8 + c2) * Tz + t0blk + u] = s_lat[c2 * 17 + u];
    }
    if (tid < NCB * 16) {
        const int i2 = tid >> 4, u = tid & 15;
        out[OCODE + ((size_t)b * NCB + i2) * Tz + t0blk + u] = s_code[i2 * 16 + u];
    }

    // ---- z_q = z - residual_final : res -> LDS transpose, re-read z, store ----
#pragma unroll 1
    for (int c = 0; c < 4; ++c) {
        if ((lane >> 4) == c) {
            const int lr = (lane & 15) * 8;
#pragma unroll
            for (int col = 0; col < 2; ++col)
#pragma unroll
                for (int j = 0; j < 8; ++j)
                    s_tr[(wave * 2 + col) * 132 + lr + j] = res2[col][j];
        }
        __syncthreads();
        {
            const int r = tid >> 2;              // 0..127
            const int u = (tid & 3) * 4;
            float4 zv = *(const float4*)(z + zbase + (size_t)(c * 128 + r) * Tz + u);
            float4 v;
            v.x = zv.x - s_tr[(u + 0) * 132 + r];
            v.y = zv.y - s_tr[(u + 1) * 132 + r];
            v.z = zv.z - s_tr[(u + 2) * 132 + r];
            v.w = zv.w - s_tr[(u + 3) * 132 + r];
            *(float4*)(out + OZQ + zbase + (size_t)(c * 128 + r) * Tz + u) = v;
        }
        __syncthreads();
    }

    // ---- loss reduction (DPP) ----
    float lt = wave_sum64(lsum);
    if (lane == 0) s_red[wave] = lt;
    __syncthreads();
    if (tid == 0) {
        float t = 0.f;
#pragma unroll
        for (int w2 = 0; w2 < 8; ++w2) t += s_red[w2];
        t *= (1.f / 524288.f);   // /(16*8*4096)
        atomicAdd(&out[OCL], t);
        atomicAdd(&out[OCL + 1], t);
    }
}

// ---------------------------------------------------------------------------
extern "C" void kernel_launch(void* const* d_in, const int* in_sizes, int n_in,
                              void* d_out, int out_size, void* d_ws, size_t ws_size,
                              hipStream_t stream) {
    (void)in_sizes; (void)n_in; (void)out_size; (void)ws_size;
    const float* z     = (const float*)d_in[0];
    const float* w_in  = (const float*)d_in[1];
    const float* b_in  = (const float*)d_in[2];
    const float* w_out = (const float*)d_in[3];
    const float* b_out = (const float*)d_in[4];
    const float* cb    = (const float*)d_in[5];
    float* ws  = (float*)d_ws;
    float* out = (float*)d_out;

    rvq_prep<<<NCB, 1024, 0, stream>>>(cb, ws, out);
    rvq_main<<<4096, 512, 0, stream>>>(z, w_in, b_in, w_out, b_out, cb, ws, out);
}